// Round 4
// baseline (746.668 us; speedup 1.0000x reference)
//
#include <hip/hip_runtime.h>
#include <hip/hip_bf16.h>

typedef __bf16  bf16x8 __attribute__((ext_vector_type(8)));
typedef __bf16  bf16x4 __attribute__((ext_vector_type(4)));
typedef float   f32x4  __attribute__((ext_vector_type(4)));
typedef int     i32x4  __attribute__((ext_vector_type(4)));

#define M_DIM 2048
#define K_DIM 2048
#define V_DIM 50257
#define V_PAD 50432                 // 197 * 256
#define BM 256
#define BN 256
#define BK 64
#define NT (K_DIM / BK)             // 32
#define SLOT_E 8192                 // elements per half-slot: 256 rows x 32 k = 16 KB

__device__ __forceinline__ void gl_lds16(const __bf16* g, __bf16* l) {
    __builtin_amdgcn_global_load_lds(
        (const __attribute__((address_space(1))) void*)g,
        (__attribute__((address_space(3))) void*)l, 16, 0, 0);
}

// ---------- prepass 1: A f32 -> bf16 (2048x2048) ----------
__global__ __launch_bounds__(256)
void cvtA(const float* __restrict__ hs, __bf16* __restrict__ a) {
    int i = (blockIdx.x * 256 + threadIdx.x) * 8;
    f32x4 v0 = *(const f32x4*)(hs + i);
    f32x4 v1 = *(const f32x4*)(hs + i + 4);
    bf16x8 t;
#pragma unroll
    for (int j = 0; j < 4; ++j) { t[j] = (__bf16)v0[j]; t[4 + j] = (__bf16)v1[j]; }
    *(bf16x8*)(a + i) = t;
}

// ---------- prepass 2: W[k][v] int32 -> Wt[v][k] bf16, zero-padded to V_PAD ----------
__global__ __launch_bounds__(256)
void cvtW(const int* __restrict__ wq, __bf16* __restrict__ wt) {
    __shared__ __attribute__((aligned(16))) __bf16 tls[64][72];
    const int t  = threadIdx.x;
    const int v0 = blockIdx.x * 64;
    const int k0 = blockIdx.y * 64;
    const int vb = t & 15, kb = t >> 4;
    const bool edge = (v0 + 64 > V_DIM);

    __bf16 cv[4][4];
#pragma unroll
    for (int j = 0; j < 4; ++j) {
        const int* p = wq + (size_t)(k0 + kb * 4 + j) * V_DIM + v0 + vb * 4;
        if (!edge) {
            i32x4 w = *(const i32x4*)p;
#pragma unroll
            for (int i = 0; i < 4; ++i) cv[j][i] = (__bf16)(float)w[i];
        } else {
#pragma unroll
            for (int i = 0; i < 4; ++i) {
                int v = v0 + vb * 4 + i;
                cv[j][i] = (v < V_DIM) ? (__bf16)(float)p[i] : (__bf16)0.0f;
            }
        }
    }
#pragma unroll
    for (int i = 0; i < 4; ++i) {
        bf16x4 c = { cv[0][i], cv[1][i], cv[2][i], cv[3][i] };
        *(bf16x4*)(&tls[vb * 4 + i][kb * 4]) = c;
    }
    __syncthreads();
    const int v = t >> 2, ko = (t & 3) * 16;
    bf16x8 r0 = *(const bf16x8*)(&tls[v][ko]);
    bf16x8 r1 = *(const bf16x8*)(&tls[v][ko + 8]);
    __bf16* op = wt + (size_t)(v0 + v) * K_DIM + k0 + ko;
    *(bf16x8*)op = r0;
    *(bf16x8*)(op + 8) = r1;
}

// ---------- main GEMM: 256x256 tile, 8-phase pipelined (T2+T3+T4+T5) ----------
// LDS: 4 A half-slots + 4 B half-slots, each [256 rows][32 k] bf16, 128 KB.
// Tile t uses slots {2(t&1), 2(t&1)+1} per operand (kk=0 / kk=1).
// Per tile 4 phases; each phase stages exactly the half-slot freed at the
// previous phase's barrier; counted vmcnt(8) (4 half-stages in flight).
// TAIL FIX (R3): stages past the last tile are issued with CLAMPED global
// addresses (never skipped) so the vmcnt instruction-count ledger stays
// uniform; they land in slots whose tiles are already finished.
__global__ __launch_bounds__(512, 1)
void lmhead_gemm_8ph(const __bf16* __restrict__ A, const __bf16* __restrict__ Bt,
                     const float* __restrict__ scale, const float* __restrict__ bias,
                     float* __restrict__ out)
{
    __shared__ __attribute__((aligned(16))) __bf16 sm[8 * SLOT_E];   // 128 KB

    const int tid  = threadIdx.x;
    const int lane = tid & 63;
    const int wv   = tid >> 6;       // 0..7
    const int wm   = wv >> 2;        // 0..1 -> 128 M rows
    const int wn   = wv & 3;         // 0..3 -> 64 N cols

    // bijective XCD-chunked swizzle: 1576 blocks = 8 * 197
    int bid  = blockIdx.x;
    int wgid = (bid & 7) * 197 + (bid >> 3);
    const int m0 = (wgid & 7) * BM;          // m fast-varying: 8 M-blocks share B-panel in L2
    const int n0 = (wgid >> 3) * BN;

    const int la = lane & 15, hi = lane >> 4;
    const int swz  = ((la >> 1) & 3) << 4;           // byte swizzle from row bits 1-2
    const int colo = ((hi * 16) ^ swz) >> 1;         // element col offset within 32-k half

    int offA[8], offB[4];
#pragma unroll
    for (int f = 0; f < 8; ++f) offA[f] = (wm * 128 + f * 16 + la) * 32 + colo;
#pragma unroll
    for (int n = 0; n < 4; ++n) offB[n] = (wn * 64 + n * 16 + la) * 32 + colo;

    // staging: lane l covers row (chunk*16 + l>>2), k-granule (l&3)^((l>>3)&3)
    const int ksl  = (((lane & 3) ^ ((lane >> 3) & 3))) * 8;   // element offset
    const int srow = lane >> 2;

    auto stageA = [&](int tt, int kk) {
        const int slot = (tt & 1) * 2 + kk;
        const int ta   = (tt < NT) ? tt : (NT - 1);   // clamp addr, keep issue count
#pragma unroll
        for (int r = 0; r < 2; ++r) {
            int chunk = wv + 8 * r;
            int row   = chunk * 16 + srow;
            gl_lds16(A + (size_t)(m0 + row) * K_DIM + ta * BK + kk * 32 + ksl,
                     sm + slot * SLOT_E + chunk * 512);
        }
    };
    auto stageB = [&](int tt, int kk) {
        const int slot = 4 + (tt & 1) * 2 + kk;
        const int ta   = (tt < NT) ? tt : (NT - 1);
#pragma unroll
        for (int r = 0; r < 2; ++r) {
            int chunk = wv + 8 * r;
            int row   = chunk * 16 + srow;
            gl_lds16(Bt + (size_t)(n0 + row) * K_DIM + ta * BK + kk * 32 + ksl,
                     sm + slot * SLOT_E + chunk * 512);
        }
    };

    f32x4 acc[8][4];
#pragma unroll
    for (int f = 0; f < 8; ++f)
#pragma unroll
        for (int n = 0; n < 4; ++n) acc[f][n] = (f32x4)(0.0f);

    // ---- prologue: 7 halves (tile0 complete + tile1 all but A-kk1) ----
    stageB(0, 0); stageA(0, 0); stageB(0, 1); stageA(0, 1);
    stageB(1, 0); stageA(1, 0); stageB(1, 1);
    asm volatile("s_waitcnt vmcnt(8)" ::: "memory");   // tile0 kk0 halves landed
    __builtin_amdgcn_s_barrier();

#pragma unroll 1
    for (int t = 0; t < NT; ++t) {
        const __bf16* As0 = sm + ((t & 1) * 2 + 0) * SLOT_E;
        const __bf16* As1 = sm + ((t & 1) * 2 + 1) * SLOT_E;
        const __bf16* Bs0 = sm + (4 + (t & 1) * 2 + 0) * SLOT_E;
        const __bf16* Bs1 = sm + (4 + (t & 1) * 2 + 1) * SLOT_E;
        bf16x8 a[4], bk[4];

        // ---- ph1: kk=0, M-frags 0-3 (8 ds_reads) ----
#pragma unroll
        for (int f = 0; f < 4; ++f) a[f]  = *(const bf16x8*)(As0 + offA[f]);
#pragma unroll
        for (int n = 0; n < 4; ++n) bk[n] = *(const bf16x8*)(Bs0 + offB[n]);
        stageA(t + 1, 1);                        // A-s1(other buf) freed at (t-1).ph4
        __builtin_amdgcn_s_setprio(1);
#pragma unroll
        for (int f = 0; f < 4; ++f)
#pragma unroll
            for (int n = 0; n < 4; ++n)
                acc[f][n] = __builtin_amdgcn_mfma_f32_16x16x32_bf16(a[f], bk[n], acc[f][n], 0, 0, 0);
        __builtin_amdgcn_s_setprio(0);
        __builtin_amdgcn_s_barrier();

        // ---- ph2: kk=0, M-frags 4-7 (4 ds_reads, B reused from regs) ----
#pragma unroll
        for (int f = 0; f < 4; ++f) a[f] = *(const bf16x8*)(As0 + offA[4 + f]);
        stageB(t + 2, 0);                        // B-s0 freed at ph1 barrier
        __builtin_amdgcn_s_setprio(1);
#pragma unroll
        for (int f = 0; f < 4; ++f)
#pragma unroll
            for (int n = 0; n < 4; ++n)
                acc[4 + f][n] = __builtin_amdgcn_mfma_f32_16x16x32_bf16(a[f], bk[n], acc[4 + f][n], 0, 0, 0);
        __builtin_amdgcn_s_setprio(0);
        asm volatile("s_waitcnt vmcnt(8)" ::: "memory");   // kk1 halves of tile t landed
        __builtin_amdgcn_s_barrier();

        // ---- ph3: kk=1, M-frags 0-3 (8 ds_reads) ----
#pragma unroll
        for (int f = 0; f < 4; ++f) a[f]  = *(const bf16x8*)(As1 + offA[f]);
#pragma unroll
        for (int n = 0; n < 4; ++n) bk[n] = *(const bf16x8*)(Bs1 + offB[n]);
        stageA(t + 2, 0);                        // A-s0 freed at ph2 barrier
        __builtin_amdgcn_s_setprio(1);
#pragma unroll
        for (int f = 0; f < 4; ++f)
#pragma unroll
            for (int n = 0; n < 4; ++n)
                acc[f][n] = __builtin_amdgcn_mfma_f32_16x16x32_bf16(a[f], bk[n], acc[f][n], 0, 0, 0);
        __builtin_amdgcn_s_setprio(0);
        __builtin_amdgcn_s_barrier();

        // ---- ph4: kk=1, M-frags 4-7 (4 ds_reads) ----
#pragma unroll
        for (int f = 0; f < 4; ++f) a[f] = *(const bf16x8*)(As1 + offA[4 + f]);
        stageB(t + 2, 1);                        // B-s1 freed at ph3 barrier
        __builtin_amdgcn_s_setprio(1);
#pragma unroll
        for (int f = 0; f < 4; ++f)
#pragma unroll
            for (int n = 0; n < 4; ++n)
                acc[4 + f][n] = __builtin_amdgcn_mfma_f32_16x16x32_bf16(a[f], bk[n], acc[4 + f][n], 0, 0, 0);
        __builtin_amdgcn_s_setprio(0);
        asm volatile("s_waitcnt vmcnt(8)" ::: "memory");   // kk0 halves of tile t+1 landed
        __builtin_amdgcn_s_barrier();
    }

    asm volatile("s_waitcnt vmcnt(0)" ::: "memory");   // drain clamped tail loads

    // ---- epilogue: D row = hi*4+r (m side), col = la (n side) ----
#pragma unroll
    for (int nf = 0; nf < 4; ++nf) {
        int n = n0 + wn * 64 + nf * 16 + la;
        bool ok = (n < V_DIM);
        int nc = ok ? n : 0;
        float sc = scale[nc];
        float bi = bias[nc];
#pragma unroll
        for (int f = 0; f < 8; ++f) {
            int m = m0 + wm * 128 + f * 16 + hi * 4;
            float* op = out + (size_t)m * V_DIM + n;
#pragma unroll
            for (int r = 0; r < 4; ++r)
                if (ok) op[(size_t)r * V_DIM] = acc[f][nf][r] * sc + bi;
        }
    }
}

// ================= fallback (R0 kernel, used only if ws too small) =================
__global__ __launch_bounds__(256, 2)
void lmhead_gemm_fb(const float* __restrict__ hs, const int* __restrict__ wq,
                    const float* __restrict__ scale, const float* __restrict__ bias,
                    float* __restrict__ out)
{
    __shared__ __attribute__((aligned(16))) __bf16 smem[2 * 2 * 128 * 64];
    const int tid  = threadIdx.x;
    const int lane = tid & 63;
    const int wv   = tid >> 6;
    const int wm   = wv >> 1, wn = wv & 1;
    const int m0   = blockIdx.x * 128;
    const int n0   = blockIdx.y * 128;
    const bool edge = (n0 + 128 > V_DIM);
    const int ngB = tid >> 3, kgB = tid & 7;

    float a_reg[4][8];
    int   b_reg[8][4];
    f32x4 acc[4][4];
#pragma unroll
    for (int i = 0; i < 4; ++i)
#pragma unroll
        for (int j = 0; j < 4; ++j) acc[i][j] = (f32x4)(0.0f);

    auto load_tile = [&](int kt) {
#pragma unroll
        for (int g = 0; g < 4; ++g) {
            int c = tid + 256 * g;
            int row = c >> 3, kg = c & 7;
            const float* p = hs + (size_t)(m0 + row) * K_DIM + (size_t)kt * 64 + kg * 8;
            f32x4 v0 = *(const f32x4*)p;
            f32x4 v1 = *(const f32x4*)(p + 4);
#pragma unroll
            for (int j = 0; j < 4; ++j) { a_reg[g][j] = v0[j]; a_reg[g][4 + j] = v1[j]; }
        }
        const int kbase = kt * 64 + kgB * 8;
        if (!edge) {
            const int* p = wq + (size_t)kbase * V_DIM + n0 + ngB * 4;
#pragma unroll
            for (int j = 0; j < 8; ++j) {
                i32x4 v = *(const i32x4*)(p + (size_t)j * V_DIM);
#pragma unroll
                for (int i = 0; i < 4; ++i) b_reg[j][i] = v[i];
            }
        } else {
#pragma unroll
            for (int j = 0; j < 8; ++j)
#pragma unroll
                for (int i = 0; i < 4; ++i) {
                    int n = n0 + ngB * 4 + i;
                    b_reg[j][i] = (n < V_DIM) ? wq[(size_t)(kbase + j) * V_DIM + n] : 0;
                }
        }
    };
    auto store_tile = [&](int buf) {
        __bf16* As = smem + buf * (2 * 128 * 64);
        __bf16* Bs = As + 128 * 64;
#pragma unroll
        for (int g = 0; g < 4; ++g) {
            int c = tid + 256 * g;
            int row = c >> 3, kg = c & 7;
            bf16x8 t;
#pragma unroll
            for (int j = 0; j < 8; ++j) t[j] = (__bf16)a_reg[g][j];
            *(bf16x8*)(As + row * 64 + ((kg * 8) ^ ((row & 7) << 3))) = t;
        }
#pragma unroll
        for (int i = 0; i < 4; ++i) {
            int row = ngB * 4 + i;
            bf16x8 t;
#pragma unroll
            for (int j = 0; j < 8; ++j) t[j] = (__bf16)(float)b_reg[j][i];
            *(bf16x8*)(Bs + row * 64 + ((kgB * 8) ^ ((row & 7) << 3))) = t;
        }
    };
    auto compute = [&](int buf) {
        const __bf16* As = smem + buf * (2 * 128 * 64);
        const __bf16* Bs = As + 128 * 64;
        const int hi = lane >> 4, la = lane & 15;
#pragma unroll
        for (int kk = 0; kk < 2; ++kk) {
            bf16x8 af[4], bfr[4];
#pragma unroll
            for (int f = 0; f < 4; ++f) {
                int row = wm * 64 + f * 16 + la;
                af[f] = *(const bf16x8*)(As + row * 64 + ((kk * 32 + hi * 8) ^ ((row & 7) << 3)));
            }
#pragma unroll
            for (int f = 0; f < 4; ++f) {
                int row = wn * 64 + f * 16 + la;
                bfr[f] = *(const bf16x8*)(Bs + row * 64 + ((kk * 32 + hi * 8) ^ ((row & 7) << 3)));
            }
#pragma unroll
            for (int fm = 0; fm < 4; ++fm)
#pragma unroll
                for (int fn = 0; fn < 4; ++fn)
                    acc[fm][fn] = __builtin_amdgcn_mfma_f32_16x16x32_bf16(
                        af[fm], bfr[fn], acc[fm][fn], 0, 0, 0);
        }
    };

    load_tile(0); store_tile(0); __syncthreads();
    int cur = 0;
#pragma unroll 1
    for (int kt = 0; kt < NT - 1; ++kt) {
        load_tile(kt + 1);
        compute(cur);
        store_tile(cur ^ 1);
        __syncthreads();
        cur ^= 1;
    }
    compute(cur);

    const int hi = lane >> 4, la = lane & 15;
#pragma unroll
    for (int fn = 0; fn < 4; ++fn) {
        int n = n0 + wn * 64 + fn * 16 + la;
        bool ok = (n < V_DIM);
        int nc = ok ? n : 0;
        float sc = scale[nc];
        float bi = bias[nc];
#pragma unroll
        for (int fm = 0; fm < 4; ++fm) {
            int m = m0 + wm * 64 + fm * 16 + hi * 4;
            float* op = out + (size_t)m * V_DIM + n;
#pragma unroll
            for (int r = 0; r < 4; ++r)
                if (ok) op[(size_t)r * V_DIM] = acc[fm][fn][r] * sc + bi;
        }
    }
}

extern "C" void kernel_launch(void* const* d_in, const int* in_sizes, int n_in,
                              void* d_out, int out_size, void* d_ws, size_t ws_size,
                              hipStream_t stream) {
    const float* hs    = (const float*)d_in[0];
    const int*   wq    = (const int*)d_in[1];
    const float* scale = (const float*)d_in[2];
    const float* bias  = (const float*)d_in[3];
    float*       out   = (float*)d_out;

    const size_t needA = (size_t)M_DIM * K_DIM * 2;               // 8 MB
    const size_t needW = (size_t)V_PAD * K_DIM * 2;               // ~206.6 MB
    if (ws_size >= needA + needW) {
        __bf16* Abf = (__bf16*)d_ws;
        __bf16* Wt  = (__bf16*)((char*)d_ws + needA);
        cvtA<<<dim3(M_DIM * K_DIM / (256 * 8)), dim3(256), 0, stream>>>(hs, Abf);
        cvtW<<<dim3(V_PAD / 64, K_DIM / 64), dim3(256), 0, stream>>>(wq, Wt);
        lmhead_gemm_8ph<<<dim3(8 * (V_PAD / BN)), dim3(512), 0, stream>>>(
            Abf, Wt, scale, bias, out);
    } else {
        lmhead_gemm_fb<<<dim3(M_DIM / 128, (V_DIM + 127) / 128), dim3(256), 0, stream>>>(
            hs, wq, scale, bias, out);
    }
}